// Round 8
// baseline (469.316 us; speedup 1.0000x reference)
//
#include <hip/hip_runtime.h>

#define BB   256
#define II   1152
#define OO   10
#define DOUT 16
#define NBLK 1024

using h2 = __fp16 __attribute__((ext_vector_type(2)));
using h4 = __fp16 __attribute__((ext_vector_type(4)));
using h8 = __fp16 __attribute__((ext_vector_type(8)));
#define H2V(v, a, b) __builtin_shufflevector((v), (v), (a), (b))
#define FD(a, b, c)  __builtin_amdgcn_fdot2((a), (b), (c), false)   // v_dot2_f32_f16

// Cross-lane reduce over the 8 dsub lanes (proven R0-R6):
// xor1/xor2 on the VALU pipe (DPP quad_perm), xor4 on DS (ds_swizzle).
__device__ __forceinline__ float dpp_add_xor1(float v) {
  int r = __builtin_amdgcn_mov_dpp(__float_as_int(v), 0xB1, 0xF, 0xF, true);
  return v + __int_as_float(r);
}
__device__ __forceinline__ float dpp_add_xor2(float v) {
  int r = __builtin_amdgcn_mov_dpp(__float_as_int(v), 0x4E, 0xF, 0xF, true);
  return v + __int_as_float(r);
}
__device__ __forceinline__ float swz_add_xor4(float v) {
  int r = __builtin_amdgcn_ds_swizzle(__float_as_int(v), 0x101F);
  return v + __int_as_float(r);
}

// Agent-scope load: reads at the device-coherent point (bypasses any stale
// per-XCD L2 copy). Pairs with device-scope atomicAdd writes.
__device__ __forceinline__ float agent_ld(const float* p) {
  return __hip_atomic_load(p, __ATOMIC_RELAXED, __HIP_MEMORY_SCOPE_AGENT);
}

// squash over the 16 Dout dims held as 8 dsub-lanes x 2 comps (proven).
__device__ __forceinline__ void squash_pair(float v0, float v1,
                                            float& o0, float& o1) {
  float sq = v0 * v0 + v1 * v1;
  sq += __shfl_xor(sq, 1);
  sq += __shfl_xor(sq, 2);
  sq += __shfl_xor(sq, 4);
  const float mag = sqrtf(sq);
  const float t1  = sq / (1.f + sq);
  o0 = t1 * (v0 / (mag + 1e-8f));
  o1 = t1 * (v1 / (mag + 1e-8f));
}

// One-time f32->f16 conversion with layout permute (proven). Kept as a
// SEPARATE dispatch: its plain stores become device-visible at the dispatch
// boundary, so the fused kernel's hot w16/x16 loads can stay plain.
__global__ __launch_bounds__(256) void convert_kernel(
    const float* __restrict__ x, const float* __restrict__ w,
    __fp16* __restrict__ x16, __fp16* __restrict__ w16)
{
  const int bid = blockIdx.x;
  if (bid < 2880) {                       // w part: 11520 rows x 64 float2
    const int t = bid * 256 + threadIdx.x;
    const int e = t & 63;
    const int r = t >> 6;                 // r = o*II + i
    const int o = r / II;
    const int i = r - o * II;
    const float2 v2 = *(const float2*)(w + (size_t)r * 128 + e * 2);
    *(h2*)(w16 + ((size_t)i * 12 + o) * 128 + e * 2) =
        __builtin_amdgcn_cvt_pkrtz(v2.x, v2.y);
  } else {                                // x part: 589824 threads x 4 floats
    const size_t t = (size_t)(bid - 2880) * 256 + threadIdx.x;
    const float4 v4 = *(const float4*)(x + t * 4);
    const h2 a = __builtin_amdgcn_cvt_pkrtz(v4.x, v4.y);
    const h2 c = __builtin_amdgcn_cvt_pkrtz(v4.z, v4.w);
    *(h4*)(x16 + t * 4) = __builtin_shufflevector(a, c, 0, 1, 2, 3);
  }
}

// Two-level software grid barrier (graph-capture-safe; no cooperative API).
// 8 spaced arrive-counters -> 1 master per phase; device-scope atomics;
// agent-scope acquire polls with s_sleep. Bounded spin: if residency ever
// fails, we bail (visible wrong answer) instead of hanging the harness.
// sync layout per phase p (uint stride 256 = 1 KB): counters at g*16, master
// at offset 128 (own 64B line). Zeroed by the launch-side memset every run.
__device__ __forceinline__ void grid_barrier(unsigned* sync, int p,
                                             int tid, int bid) {
  __syncthreads();                       // block's lanes done with the phase
  if (tid == 0) {
    __threadfence();                     // order my writes before arrive
    unsigned* cnt    = sync + p * 256 + (bid & 7) * 16;
    unsigned* master = sync + p * 256 + 128;
    const unsigned a = __hip_atomic_fetch_add(cnt, 1, __ATOMIC_ACQ_REL,
                                              __HIP_MEMORY_SCOPE_AGENT);
    if (a + 1 == (NBLK / 8))
      __hip_atomic_fetch_add(master, 1, __ATOMIC_ACQ_REL,
                             __HIP_MEMORY_SCOPE_AGENT);
    int spins = 0;
    while (__hip_atomic_load(master, __ATOMIC_ACQUIRE,
                             __HIP_MEMORY_SCOPE_AGENT) < 8u) {
      __builtin_amdgcn_s_sleep(8);
      if (++spins > (1 << 20)) break;    // ~0.2 s bail-out, never hang
    }
  }
  __syncthreads();                       // release the block's lanes
}

// One routing phase = exactly the R6 pass body (LDS-free w reads straight
// from L2, batched 10 dwordx4 halves, fdot2 chains, dpp/swz softmax reduce).
// In-kernel coherence: plane accumulation via PLAIN atomicAdd (HIP device
// scope -> coherent across XCDs within one dispatch), plane reads agent_ld.
// K=0: plain sum (c=0.1). K=1: V from plane0. K=2: V from plane0+plane1.
template<int K>
__device__ __forceinline__ void phase(
    const __fp16* __restrict__ x16, const __fp16* __restrict__ w16,
    const float* __restrict__ r0, const float* __restrict__ r1,
    float* __restrict__ plane, float (*red)[8 * 168],
    const int wv, const int dsub, const int bl, const int b, const int i0)
{
  float Vr[OO][2];
  if (K >= 1) {
#pragma unroll
    for (int o = 0; o < OO; ++o) {
      const float* pp = r0 + ((size_t)b * OO + o) * DOUT + dsub * 2;
      float v0, v1;
      squash_pair(agent_ld(pp), agent_ld(pp + 1), v0, v1);
      if (K == 2) {
        const float* qq = r1 + ((size_t)b * OO + o) * DOUT + dsub * 2;
        float u0, u1;
        squash_pair(agent_ld(qq), agent_ld(qq + 1), u0, u1);
        v0 += u0; v1 += u1;              // b-linearity: t(V0+V1) = t(V0)+t(V1)
      }
      Vr[o][0] = v0; Vr[o][1] = v1;
    }
  }

  float s[OO][2];
#pragma unroll
  for (int o = 0; o < OO; ++o) { s[o][0] = 0.f; s[o][1] = 0.f; }

  const __fp16* wp = w16 + (size_t)i0 * 1536 + dsub * 16;
  const __fp16* xp = x16 + ((size_t)b * II + i0) * 8;
  h8 xq = *(const h8*)(xp);
  h8 xn = *(const h8*)(xp + 8);

#pragma unroll 1
  for (int ii = 0; ii < 9; ++ii) {
    const h2 xq0 = H2V(xq, 0, 1), xq1 = H2V(xq, 2, 3);
    const h2 xq2 = H2V(xq, 4, 5), xq3 = H2V(xq, 6, 7);

    float xh[OO][2];
    float t[OO];
#pragma unroll
    for (int half = 0; half < 2; ++half) {
      h8 wz[10];
      const __fp16* base = wp + half * 640;              // 5 o's x 128 els
#pragma unroll
      for (int g = 0; g < 5; ++g) {
        wz[2 * g]     = *(const h8*)(base + g * 128);    // d even: 8 c's
        wz[2 * g + 1] = *(const h8*)(base + g * 128 + 8);// d odd:  8 c's
      }
      __builtin_amdgcn_sched_barrier(0);   // keep the 10 loads batched
#pragma unroll
      for (int g = 0; g < 5; ++g) {
        const int o = half * 5 + g;
        xh[o][0] = FD(H2V(wz[2*g], 0, 1), xq0, FD(H2V(wz[2*g], 2, 3), xq1,
                   FD(H2V(wz[2*g], 4, 5), xq2, FD(H2V(wz[2*g], 6, 7), xq3, 0.f))));
        xh[o][1] = FD(H2V(wz[2*g+1], 0, 1), xq0, FD(H2V(wz[2*g+1], 2, 3), xq1,
                   FD(H2V(wz[2*g+1], 4, 5), xq2, FD(H2V(wz[2*g+1], 6, 7), xq3, 0.f))));
        if (K >= 1)
          t[o] = Vr[o][0] * xh[o][0] + Vr[o][1] * xh[o][1];
      }
    }

    if (K == 0) {
#pragma unroll
      for (int o = 0; o < OO; ++o) { s[o][0] += xh[o][0]; s[o][1] += xh[o][1]; }
    } else {
#pragma unroll
      for (int o = 0; o < OO; ++o) {   // reduce over the 8 dsub lanes
        t[o] = dpp_add_xor1(t[o]);
        t[o] = dpp_add_xor2(t[o]);
        t[o] = swz_add_xor4(t[o]);
      }
      float sum = 0.f;
#pragma unroll
      for (int o = 0; o < OO; ++o) { t[o] = __expf(t[o]); sum += t[o]; }
      const float inv = __builtin_amdgcn_rcpf(sum);  // |t|<1 pre-exp; 1-ulp ok
#pragma unroll
      for (int o = 0; o < OO; ++o) {
        const float c = t[o] * inv;
        s[o][0] += c * xh[o][0];
        s[o][1] += c * xh[o][1];
      }
    }

    wp += 1536;
    xq = xn;
    const int inx = (ii < 7) ? (i0 + ii + 2) : (i0 + 8);
    xn = *(const h8*)(x16 + ((size_t)b * II + inx) * 8);
  }

  if (K == 0) {
#pragma unroll
    for (int o = 0; o < OO; ++o) { s[o][0] *= 0.1f; s[o][1] *= 0.1f; }
  }

  // cross-wave reduce (proven), then device-scope atomic accumulate.
  if (wv != 0) {
    float* rr = red[wv] + bl * 168;    // padded rows: 2-way banks (free)
#pragma unroll
    for (int o = 0; o < OO; ++o)
      *(float2*)&rr[o * 16 + dsub * 2] = make_float2(s[o][0], s[o][1]);
  }
  __syncthreads();
  if (wv == 0) {
    float* outp = plane + (size_t)b * (OO * DOUT);
#pragma unroll
    for (int o = 0; o < OO; ++o) {
      float a0 = s[o][0], a1 = s[o][1];
#pragma unroll
      for (int r = 1; r < 4; ++r) {
        const float2 v2 = *(const float2*)(red[r] + bl * 168 + o * 16 + dsub * 2);
        a0 += v2.x; a1 += v2.y;
      }
      atomicAdd(&outp[o * 16 + dsub * 2],     a0);   // device scope: coherent
      atomicAdd(&outp[o * 16 + dsub * 2 + 1], a1);
    }
  }
}

// All 3 routing iterations + final squash in ONE ordinary (capturable)
// kernel. 1024 blocks = exactly 4/CU x 256 CU, guaranteed resident
// (launch_bounds(256,4) caps VGPR at 128; LDS 21.5 KB -> 4 blocks/CU by
// both limits), so the software grid barrier converges.
__global__ __launch_bounds__(256, 4) void fused_kernel(
    const __fp16* __restrict__ x16,  // f16 [B][I][8]
    const __fp16* __restrict__ w16,  // f16 [I][12][16][8]
    float* __restrict__ p0, float* __restrict__ p1, float* __restrict__ p2,
    unsigned* __restrict__ sync,     // barrier counters (pre-zeroed)
    float* __restrict__ out)         // fp32 [B][O][16]
{
  const int tid  = threadIdx.x;
  const int bid  = blockIdx.x;
  const int lane = tid & 63;
  const int wv   = tid >> 6;
  const int dsub = lane & 7;          // d-pair index (d = 2*dsub + dlo)
  const int bl   = lane >> 3;         // batch-in-wave (8)
  const int icg  = bid & 31;          // i-group (4 wave-chunks of 9); fast
  const int bg   = bid >> 5;          // 32 groups of 8 b
  const int b    = bg * 8 + bl;
  const int i0   = (icg * 4 + wv) * 9;

  __shared__ float red[4][8 * 168];   // cross-wave reduce (21.5 KB)

  phase<0>(x16, w16, nullptr, nullptr, p0, red, wv, dsub, bl, b, i0);
  grid_barrier(sync, 0, tid, bid);

  phase<1>(x16, w16, p0, nullptr, p1, red, wv, dsub, bl, b, i0);
  grid_barrier(sync, 1, tid, bid);

  phase<2>(x16, w16, p0, p1, p2, red, wv, dsub, bl, b, i0);
  grid_barrier(sync, 2, tid, bid);

  if (icg == 0 && wv == 0) {          // final squash -> out; one writer per b
#pragma unroll
    for (int o = 0; o < OO; ++o) {
      const float* pp = p2 + ((size_t)b * OO + o) * DOUT + dsub * 2;
      float u0, u1;
      squash_pair(agent_ld(pp), agent_ld(pp + 1), u0, u1);
      *(float2*)(out + ((size_t)b * OO + o) * DOUT + dsub * 2) =
          make_float2(u0, u1);
    }
  }
}

extern "C" void kernel_launch(void* const* d_in, const int* in_sizes, int n_in,
                              void* d_out, int out_size, void* d_ws, size_t ws_size,
                              hipStream_t stream) {
  const float* x = (const float*)d_in[0];   // fp32 [256,1152,8]
  const float* w = (const float*)d_in[1];   // fp32 [10,1152,16,8]
  float* outp = (float*)d_out;              // fp32 [256,10,16]

  const size_t P = (size_t)BB * OO * DOUT;  // 40960 floats per plane
  float* s0 = (float*)d_ws;                 // 3 accumulator planes
  float* s1 = s0 + P;
  float* s2 = s1 + P;
  unsigned* sync = (unsigned*)(s2 + P);            // 3 KB barrier counters
  __fp16* x16 = (__fp16*)(sync + 1024);            // 4.72 MB
  __fp16* w16 = x16 + (size_t)BB * II * 8;         // 3.54 MB (o-padded tiles)

  // zero the 3 planes + barrier counters (one memset: planes and sync are
  // contiguous by construction above)
  hipMemsetAsync(s0, 0, 3 * P * sizeof(float) + 1024 * sizeof(unsigned), stream);
  convert_kernel<<<5184, 256, 0, stream>>>(x, w, x16, w16);

  fused_kernel<<<NBLK, 256, 0, stream>>>(x16, w16, s0, s1, s2, sync, outp);
}

// Round 9
// 157.694 us; speedup vs baseline: 2.9761x; 2.9761x over previous
//
#include <hip/hip_runtime.h>

#define BB   256
#define II   1152
#define OO   10
#define DOUT 16
#define NICG 32                       // i-chunk groups = partial-plane slots

using h2 = __fp16 __attribute__((ext_vector_type(2)));
using h4 = __fp16 __attribute__((ext_vector_type(4)));
using h8 = __fp16 __attribute__((ext_vector_type(8)));
#define H2V(v, a, b) __builtin_shufflevector((v), (v), (a), (b))
#define FD(a, b, c)  __builtin_amdgcn_fdot2((a), (b), (c), false)   // v_dot2_f32_f16

// Cross-lane reduce over the 8 dsub lanes (proven R0-R8):
// xor1/xor2 on the VALU pipe (DPP quad_perm), xor4 on DS (ds_swizzle).
__device__ __forceinline__ float dpp_add_xor1(float v) {
  int r = __builtin_amdgcn_mov_dpp(__float_as_int(v), 0xB1, 0xF, 0xF, true);
  return v + __int_as_float(r);
}
__device__ __forceinline__ float dpp_add_xor2(float v) {
  int r = __builtin_amdgcn_mov_dpp(__float_as_int(v), 0x4E, 0xF, 0xF, true);
  return v + __int_as_float(r);
}
__device__ __forceinline__ float swz_add_xor4(float v) {
  int r = __builtin_amdgcn_ds_swizzle(__float_as_int(v), 0x101F);
  return v + __int_as_float(r);
}

// squash over the 16 Dout dims held as 8 dsub-lanes x 2 comps (proven).
__device__ __forceinline__ void squash_pair(float v0, float v1,
                                            float& o0, float& o1) {
  float sq = v0 * v0 + v1 * v1;
  sq += __shfl_xor(sq, 1);
  sq += __shfl_xor(sq, 2);
  sq += __shfl_xor(sq, 4);
  const float mag = sqrtf(sq);
  const float t1  = sq / (1.f + sq);
  o0 = t1 * (v0 / (mag + 1e-8f));
  o1 = t1 * (v1 / (mag + 1e-8f));
}

// One-time f32->f16 conversion with layout permute (proven).
//   w: [O][I][16][8] f32 -> w16: [I][12(o-pad)][16][8] f16
//   x: [B][I][8] f32     -> x16: [B][I][8] f16 (rtz)
__global__ __launch_bounds__(256) void convert_kernel(
    const float* __restrict__ x, const float* __restrict__ w,
    __fp16* __restrict__ x16, __fp16* __restrict__ w16)
{
  const int bid = blockIdx.x;
  if (bid < 2880) {                       // w part: 11520 rows x 64 float2
    const int t = bid * 256 + threadIdx.x;
    const int e = t & 63;
    const int r = t >> 6;                 // r = o*II + i
    const int o = r / II;
    const int i = r - o * II;
    const float2 v2 = *(const float2*)(w + (size_t)r * 128 + e * 2);
    *(h2*)(w16 + ((size_t)i * 12 + o) * 128 + e * 2) =
        __builtin_amdgcn_cvt_pkrtz(v2.x, v2.y);
  } else {                                // x part: 589824 threads x 4 floats
    const size_t t = (size_t)(bid - 2880) * 256 + threadIdx.x;
    const float4 v4 = *(const float4*)(x + t * 4);
    const h2 a = __builtin_amdgcn_cvt_pkrtz(v4.x, v4.y);
    const h2 c = __builtin_amdgcn_cvt_pkrtz(v4.z, v4.w);
    *(h4*)(x16 + t * 4) = __builtin_shufflevector(a, c, 0, 1, 2, 3);
  }
}

// Pass kernel — R6 body (global-direct L2-resident w reads, batched 10
// dwordx4 halves, fdot2 chains, dpp/swz softmax reduce), with the ATOMIC
// TAIL REPLACED by a contention-free private-slot store:
//   partial[icg][b][160] <- this block's i-chunk sum (plain float2 stores).
// No atomics, no pre-zeroing, no cross-block interaction of any kind.
// K=0: plain sum (c=0.1). K=1: V from plane0. K=2: V from plane0+plane1.
template<int K>
__global__ __launch_bounds__(256, 4) void pass_kernel(
    const __fp16* __restrict__ x16,  // f16 [B][I][8]
    const __fp16* __restrict__ w16,  // f16 [I][12][16][8]
    const float* __restrict__ r0,    // plane0 (K>=1), dense [B][O][16]
    const float* __restrict__ r1,    // plane1 (K==2)
    float* __restrict__ partial)     // f32 [NICG][B][160] private slots
{
  const int tid  = threadIdx.x;
  const int lane = tid & 63;
  const int wv   = tid >> 6;
  const int dsub = lane & 7;          // d-pair index (d = 2*dsub + dlo)
  const int bl   = lane >> 3;         // batch-in-wave (8)
  const int icg  = blockIdx.x & 31;   // i-group (4 wave-chunks of 9); fast
  const int bg   = blockIdx.x >> 5;   // 32 groups of 8 b
  const int b    = bg * 8 + bl;
  const int i0   = (icg * 4 + wv) * 9;

  __shared__ float red[4][8 * 168];   // cross-wave reduce (21.5 KB)

  // V prologue: each lane squashes its own (b,o,d-pair) slice (proven).
  float Vr[OO][2];
  if (K >= 1) {
#pragma unroll
    for (int o = 0; o < OO; ++o) {
      const float2 a = *(const float2*)(r0 + ((size_t)b * OO + o) * DOUT + dsub * 2);
      float v0, v1;
      squash_pair(a.x, a.y, v0, v1);
      if (K == 2) {
        const float2 c = *(const float2*)(r1 + ((size_t)b * OO + o) * DOUT + dsub * 2);
        float u0, u1;
        squash_pair(c.x, c.y, u0, u1);
        v0 += u0; v1 += u1;            // b-linearity: t(V0+V1) = t(V0)+t(V1)
      }
      Vr[o][0] = v0; Vr[o][1] = v1;
    }
  }

  float s[OO][2];
#pragma unroll
  for (int o = 0; o < OO; ++o) { s[o][0] = 0.f; s[o][1] = 0.f; }

  const __fp16* wp = w16 + (size_t)i0 * 1536 + dsub * 16;
  const __fp16* xp = x16 + ((size_t)b * II + i0) * 8;
  h8 xq = *(const h8*)(xp);
  h8 xn = *(const h8*)(xp + 8);

#pragma unroll 1
  for (int ii = 0; ii < 9; ++ii) {
    const h2 xq0 = H2V(xq, 0, 1), xq1 = H2V(xq, 2, 3);
    const h2 xq2 = H2V(xq, 4, 5), xq3 = H2V(xq, 6, 7);

    float xh[OO][2];
    float t[OO];
#pragma unroll
    for (int half = 0; half < 2; ++half) {
      h8 wz[10];
      const __fp16* base = wp + half * 640;              // 5 o's x 128 els
#pragma unroll
      for (int g = 0; g < 5; ++g) {
        wz[2 * g]     = *(const h8*)(base + g * 128);    // d even: 8 c's
        wz[2 * g + 1] = *(const h8*)(base + g * 128 + 8);// d odd:  8 c's
      }
      __builtin_amdgcn_sched_barrier(0);   // keep the 10 loads batched
#pragma unroll
      for (int g = 0; g < 5; ++g) {
        const int o = half * 5 + g;
        xh[o][0] = FD(H2V(wz[2*g], 0, 1), xq0, FD(H2V(wz[2*g], 2, 3), xq1,
                   FD(H2V(wz[2*g], 4, 5), xq2, FD(H2V(wz[2*g], 6, 7), xq3, 0.f))));
        xh[o][1] = FD(H2V(wz[2*g+1], 0, 1), xq0, FD(H2V(wz[2*g+1], 2, 3), xq1,
                   FD(H2V(wz[2*g+1], 4, 5), xq2, FD(H2V(wz[2*g+1], 6, 7), xq3, 0.f))));
        if (K >= 1)
          t[o] = Vr[o][0] * xh[o][0] + Vr[o][1] * xh[o][1];
      }
    }

    if (K == 0) {
#pragma unroll
      for (int o = 0; o < OO; ++o) { s[o][0] += xh[o][0]; s[o][1] += xh[o][1]; }
    } else {
#pragma unroll
      for (int o = 0; o < OO; ++o) {   // reduce over the 8 dsub lanes
        t[o] = dpp_add_xor1(t[o]);
        t[o] = dpp_add_xor2(t[o]);
        t[o] = swz_add_xor4(t[o]);
      }
      float sum = 0.f;
#pragma unroll
      for (int o = 0; o < OO; ++o) { t[o] = __expf(t[o]); sum += t[o]; }
      const float inv = __builtin_amdgcn_rcpf(sum);  // |t|<1 pre-exp; 1-ulp ok
#pragma unroll
      for (int o = 0; o < OO; ++o) {
        const float c = t[o] * inv;
        s[o][0] += c * xh[o][0];
        s[o][1] += c * xh[o][1];
      }
    }

    wp += 1536;
    xq = xn;
    const int inx = (ii < 7) ? (i0 + ii + 2) : (i0 + 8);
    xn = *(const h8*)(x16 + ((size_t)b * II + inx) * 8);
  }

  if (K == 0) {
#pragma unroll
    for (int o = 0; o < OO; ++o) { s[o][0] *= 0.1f; s[o][1] *= 0.1f; }
  }

  // cross-wave reduce (proven), then PLAIN coalesced store to this block's
  // private partial slot — zero contention, zero atomics.
  if (wv != 0) {
    float* rr = red[wv] + bl * 168;    // padded rows: 2-way banks (free)
#pragma unroll
    for (int o = 0; o < OO; ++o)
      *(float2*)&rr[o * 16 + dsub * 2] = make_float2(s[o][0], s[o][1]);
  }
  __syncthreads();
  if (wv == 0) {
    float* outp = partial + ((size_t)icg * BB + b) * (OO * DOUT);
#pragma unroll
    for (int o = 0; o < OO; ++o) {
      float a0 = s[o][0], a1 = s[o][1];
#pragma unroll
      for (int r = 1; r < 4; ++r) {
        const float2 v2 = *(const float2*)(red[r] + bl * 168 + o * 16 + dsub * 2);
        a0 += v2.x; a1 += v2.y;
      }
      *(float2*)&outp[o * 16 + dsub * 2] = make_float2(a0, a1);
    }
  }
}

// Sum the 32 partial slots into a dense plane (40960 cells, 160 blocks).
// 32 independent strided loads per thread; consecutive threads are
// consecutive cells -> coalesced within each slot slice.
__global__ __launch_bounds__(256) void reduce_plane(
    const float* __restrict__ partial,   // [NICG][B*160]
    float* __restrict__ plane)           // [B*160]
{
  const int idx = blockIdx.x * 256 + threadIdx.x;
  float s = 0.f;
#pragma unroll
  for (int g = 0; g < NICG; ++g)
    s += partial[(size_t)g * (BB * OO * DOUT) + idx];
  plane[idx] = s;
}

// Last reduce folds the final squash (16 d-cells of a (b,o) live in 16
// adjacent lanes -> shfl_xor 1/2/4/8, the proven final_kernel pattern).
__global__ __launch_bounds__(256) void reduce_final(
    const float* __restrict__ partial,   // [NICG][B*160]
    float* __restrict__ out)             // fp32 [B][O][16]
{
  const int idx = blockIdx.x * 256 + threadIdx.x;
  float s = 0.f;
#pragma unroll
  for (int g = 0; g < NICG; ++g)
    s += partial[(size_t)g * (BB * OO * DOUT) + idx];

  float sq = s * s;
  sq += __shfl_xor(sq, 1);
  sq += __shfl_xor(sq, 2);
  sq += __shfl_xor(sq, 4);
  sq += __shfl_xor(sq, 8);
  const float mag = sqrtf(sq);
  out[idx] = sq / (1.f + sq) * (s / (mag + 1e-8f));
}

extern "C" void kernel_launch(void* const* d_in, const int* in_sizes, int n_in,
                              void* d_out, int out_size, void* d_ws, size_t ws_size,
                              hipStream_t stream) {
  const float* x = (const float*)d_in[0];   // fp32 [256,1152,8]
  const float* w = (const float*)d_in[1];   // fp32 [10,1152,16,8]
  float* outp = (float*)d_out;              // fp32 [256,10,16]

  const size_t P = (size_t)BB * OO * DOUT;  // 40960 floats per plane
  float* plane0  = (float*)d_ws;
  float* plane1  = plane0 + P;
  float* partial = plane1 + P;                     // 32*40960 f = 5.24 MB
  __fp16* x16 = (__fp16*)(partial + (size_t)NICG * P);   // 4.72 MB
  __fp16* w16 = x16 + (size_t)BB * II * 8;               // 3.54 MB

  convert_kernel<<<5184, 256, 0, stream>>>(x, w, x16, w16);

  const int pg = 1024;                      // 32 icg (fast) x 32 bg
  const int rg = (int)(P / 256);            // 160 blocks

  pass_kernel<0><<<pg, 256, 0, stream>>>(x16, w16, nullptr, nullptr, partial);
  reduce_plane<<<rg, 256, 0, stream>>>(partial, plane0);
  pass_kernel<1><<<pg, 256, 0, stream>>>(x16, w16, plane0, nullptr, partial);
  reduce_plane<<<rg, 256, 0, stream>>>(partial, plane1);
  pass_kernel<2><<<pg, 256, 0, stream>>>(x16, w16, plane0, plane1, partial);
  reduce_final<<<rg, 256, 0, stream>>>(partial, outp);
}